// Round 1
// baseline (515.671 us; speedup 1.0000x reference)
//
#include <hip/hip_runtime.h>
#include <stdint.h>

// CTC loss forward, MI355X.
// Phase 1 (k_gather_exp): block per (b,t) row; stage the 4KB vocab row into
//   LDS with coalesced float4 loads (256 thr x 16B), then gather the 256
//   target emissions + blank from LDS (random banks ~ free), exp(),
//   coalesced compact store.
//   El[b][t][d] = exp(lp[b,t,tgt[b,d]]), Eb[b][t] = exp(lp[b,t,0]).
// Phase 2 (k_ctc_alpha): one wave per sample; linear-domain alpha with
//   per-lane power-of-2 offsets (renorm every 4 steps, no transcendentals).
//   Emissions streamed global->REGISTERS via a 16-step rotating pipeline
//   (static slot indices, unroll-by-16): lane i loads El[t][4i..4i+3] as one
//   coalesced dwordx4, Eb[t] is a wave-uniform (scalar) load.
//   __launch_bounds__(64, 1): only 32 waves run on the whole chip, so cap
//   occupancy at 1 wave/EU and give the allocator the full 512-VGPR budget —
//   otherwise the compiler sinks the refill loads next to their uses
//   (VGPR_Count was 68 < the 64 VGPRs the pipeline payload needs) and every
//   step eats the full L2/L3 latency.
//   Cross-lane shift-by-1 via DPP wave_shr1 (VALU latency, not DS).
// Phase 3 (k_reduce): mean over batch of nll/target_length.

#define LN2F 0.69314718055994530942f
#define PD 16  // register pipeline depth (steps)

// lane i <- lane i-1, lane 0 <- 0 (DPP wave_shr1, bound_ctrl=1)
__device__ __forceinline__ float shr1f(float x) {
  return __int_as_float(
      __builtin_amdgcn_update_dpp(0, __float_as_int(x), 0x138, 0xF, 0xF, true));
}
__device__ __forceinline__ int shr1i(int x) {
  return __builtin_amdgcn_update_dpp(0, x, 0x138, 0xF, 0xF, true);
}

__global__ __launch_bounds__(256) void k_gather_exp(
    const float* __restrict__ lp, const int* __restrict__ tgt,
    const int* __restrict__ ilen, float* __restrict__ El,
    float* __restrict__ Eb, int T, int V, int S) {
  const int b = blockIdx.y;
  const int t = blockIdx.x;
  if (t >= ilen[b]) return;  // phase 2 never reads t >= T_b
  const int tid = threadIdx.x;  // S == 256 == blockDim
  __shared__ float row_s[1024];  // V == 1024
  const float* row = lp + ((size_t)b * T + t) * V;
  // coalesced stage: 256 threads x 16B = 4KB row
  *(float4*)(row_s + 4 * tid) = *(const float4*)(row + 4 * tid);
  __syncthreads();
  const int lab = tgt[b * S + tid];
  El[((size_t)b * T + t) * S + tid] = __expf(row_s[lab]);
  if (tid == 0) Eb[(size_t)b * T + t] = __expf(row_s[0]);
}

__global__ __launch_bounds__(64, 1) void k_ctc_alpha(
    const float* __restrict__ El, const float* __restrict__ Eb,
    const int* __restrict__ tgt, const int* __restrict__ ilen,
    const int* __restrict__ tlen, float* __restrict__ nll_out, int T, int S) {
  const int b = blockIdx.x;
  const int lane = threadIdx.x;
  const bool l0 = (lane == 0);

  const int Tb = ilen[b];
  const int U = tlen[b];

  // skip flags per pair p = 4*lane + j
  const int4 tg = *(const int4*)(tgt + (size_t)b * S + 4 * lane);
  const int tprev = __shfl_up(tg.w, 1);
  const float sk0 = (l0 || tg.x != tprev) ? 1.0f : 0.0f;
  const float sk1 = (tg.y != tg.x) ? 1.0f : 0.0f;
  const float sk2 = (tg.z != tg.y) ? 1.0f : 0.0f;
  const float sk3 = (tg.w != tg.z) ? 1.0f : 0.0f;

  const float* Elb = El + (size_t)b * T * 256;
  const float* Ebb = Eb + (size_t)b * T;

  // lane owns pairs p=4*lane..4*lane+3 (states 2p+1 label, 2p+2 blank);
  // a0 = state 0 (lane 0 only). true alpha = a * 2^o (per-lane offset).
  // t = 0 init: only states 0,1 live.
  float a0 = l0 ? Ebb[0] : 0.0f;
  float aL0 = l0 ? Elb[0] : 0.0f;
  float aL1 = 0, aL2 = 0, aL3 = 0;
  float aB0 = 0, aB1 = 0, aB2 = 0, aB3 = 0;
  int o = 0;
  float s = 1.0f;  // 2^(o_left - o)

  auto stepf = [&](float4 el, float eb) {  // generic step (t > 0)
    float pL = shr1f(aL3) * s;  // state 2p-1 for p = 4*lane
    float pB = shr1f(aB3) * s;  // state 2p
    pL = l0 ? 0.0f : pL;
    pB = l0 ? a0 : pB;
    const float nB0 = (aB0 + aL0) * eb;
    const float nB1 = (aB1 + aL1) * eb;
    const float nB2 = (aB2 + aL2) * eb;
    const float nB3 = (aB3 + aL3) * eb;
    const float nL0 = (aL0 + fmaf(sk0, pL, pB)) * el.x;
    const float nL1 = (aL1 + fmaf(sk1, aL0, aB0)) * el.y;
    const float nL2 = (aL2 + fmaf(sk2, aL1, aB1)) * el.z;
    const float nL3 = (aL3 + fmaf(sk3, aL2, aB2)) * el.w;
    a0 *= eb;
    aL0 = nL0; aL1 = nL1; aL2 = nL2; aL3 = nL3;
    aB0 = nB0; aB1 = nB1; aB2 = nB2; aB3 = nB3;
  };
  auto renorm = [&]() {  // per-lane power-of-2 rescale (no transcendentals)
    float m = fmaxf(fmaxf(fmaxf(aL0, aL1), fmaxf(aL2, aL3)),
                    fmaxf(fmaxf(aB0, aB1), fmaxf(aB2, aB3)));
    m = fmaxf(m, a0);
    const bool nz = (m > 0.0f);
    const int mk = nz ? (((__float_as_int(m) >> 23) & 0xff) - 126) : 0;
    const int ocand = o + mk;
    const int oleft = shr1i(ocand);
    o = (nz || l0) ? ocand : oleft;  // zero lanes adopt left offset
    const float sc = nz ? __int_as_float((127 - mk) << 23) : 1.0f;
    aL0 *= sc; aL1 *= sc; aL2 *= sc; aL3 *= sc;
    aB0 *= sc; aB1 *= sc; aB2 *= sc; aB3 *= sc;
    a0 *= sc;
    int d = shr1i(o) - o;
    d = max(-126, min(126, d));
    s = __int_as_float((d + 127) << 23);  // 2^d
  };

  // register pipeline: slot j holds emissions for row t = base + j
  float4 pel[PD];
  float peb[PD];
  const int lo4 = 4 * lane;

#pragma unroll
  for (int j = 0; j < PD; ++j) {  // prologue: rows 1..16 (Tb >= 17 assumed)
    const int row = min(j + 1, Tb - 1);
    pel[j] = *(const float4*)(Elb + ((size_t)row << 8) + lo4);
    peb[j] = Ebb[row];
  }

  const int R = Tb - 1;       // generic steps t = 1..Tb-1
  const int nfull = R >> 4;
  const int rem = R & 15;

  for (int k = 0; k < nfull; ++k) {
    const int base = 1 + (k << 4);
#pragma unroll
    for (int j = 0; j < PD; ++j) {
      const float4 el = pel[j];
      const float eb = peb[j];
      const int row = min(base + PD + j, Tb - 1);  // refill slot j
      pel[j] = *(const float4*)(Elb + ((size_t)row << 8) + lo4);
      peb[j] = Ebb[row];
      stepf(el, eb);
      // t = base + j, base ≡ 1 (mod 16) → (t&3)==3 ⇔ (j&3)==2
      if ((j & 3) == 2) renorm();
    }
  }
  {  // tail: remaining rem steps, slots 0..rem-1 already loaded
#pragma unroll
    for (int j = 0; j < PD; ++j) {
      if (j < rem) {
        stepf(pel[j], peb[j]);
        if ((j & 3) == 2) renorm();
      }
    }
  }

  // alpha_{Tb-1} at states 2U (pair U-1 blank) and 2U-1 (pair U-1 label)
  if (lane == ((U - 1) >> 2)) {
    const int j = (U - 1) & 3;
    float sv;
    if (j == 0)      sv = aL0 + aB0;
    else if (j == 1) sv = aL1 + aB1;
    else if (j == 2) sv = aL2 + aB2;
    else             sv = aL3 + aB3;
    float nll = -LN2F * (__log2f(sv) + (float)o);
    if (!(nll < 5e29f)) nll = 0.0f;  // zero_infinity (catches NaN/inf)
    nll_out[b] = nll / (float)U;
  }
}

__global__ __launch_bounds__(64) void k_reduce(const float* __restrict__ nll,
                                               float* __restrict__ out,
                                               int B) {
  float v = 0.0f;
  for (int i = threadIdx.x; i < B; i += 64) v += nll[i];
  for (int off = 32; off > 0; off >>= 1) v += __shfl_down(v, off);
  if (threadIdx.x == 0) out[0] = v / (float)B;
}

extern "C" void kernel_launch(void* const* d_in, const int* in_sizes, int n_in,
                              void* d_out, int out_size, void* d_ws,
                              size_t ws_size, hipStream_t stream) {
  const float* lp = (const float*)d_in[0];
  const int* tgt = (const int*)d_in[1];
  const int* ilen = (const int*)d_in[2];
  const int* tlen = (const int*)d_in[3];

  const int B = in_sizes[2];
  const int S = in_sizes[1] / B;                               // 256
  const int V = 1024;                                          // fixed by problem
  const int T = (int)((size_t)in_sizes[0] / ((size_t)B * V));  // 2000

  float* El = (float*)d_ws;                 // B*T*S f32
  float* Eb = El + (size_t)B * T * S;       // B*T f32
  float* nw = Eb + (size_t)B * T;           // B f32

  dim3 g1(T, B);
  k_gather_exp<<<g1, 256, 0, stream>>>(lp, tgt, ilen, El, Eb, T, V, S);
  k_ctc_alpha<<<B, 64, 0, stream>>>(El, Eb, tgt, ilen, tlen, nw, T, S);
  k_reduce<<<1, 64, 0, stream>>>(nw, (float*)d_out, B);
}